// Round 2
// baseline (350.752 us; speedup 1.0000x reference)
//
#include <hip/hip_runtime.h>
#include <hip/hip_bf16.h>
#include <math.h>

// out[b] = tanh(tanh(dot(x[b,:], w) + b0)), x: [16384, 4096] f32, w: [4096] f32, b: [1] f32
// Memory-bound matvec: one 64-lane wave per row, float4 loads, shfl reduction.

#define BATCH    16384
#define IN_SIZE  4096
#define VEC4     (IN_SIZE / 4)   // 1024 float4 per row

__global__ __launch_bounds__(256) void cartnn_matvec_tanh(
    const float* __restrict__ x,
    const float* __restrict__ w,
    const float* __restrict__ b,
    float* __restrict__ out)
{
    const int lane = threadIdx.x & 63;
    const int waveInBlock = threadIdx.x >> 6;          // 0..3
    const int row = blockIdx.x * 4 + waveInBlock;      // one wave per row

    const float4* __restrict__ x4 = reinterpret_cast<const float4*>(x) + (size_t)row * VEC4;
    const float4* __restrict__ w4 = reinterpret_cast<const float4*>(w);

    // 1024 float4 / 64 lanes = 16 iterations; lane-contiguous (coalesced, 16 B/lane).
    // Two independent accumulators -> 2x ILP on the FMA chain.
    float acc0 = 0.0f, acc1 = 0.0f;
    #pragma unroll
    for (int k = lane; k < VEC4; k += 128) {
        float4 xv0 = x4[k];
        float4 wv0 = w4[k];          // 16 KiB total, L1/L2-resident across all waves
        float4 xv1 = x4[k + 64];
        float4 wv1 = w4[k + 64];
        acc0 = fmaf(xv0.x, wv0.x, acc0);
        acc0 = fmaf(xv0.y, wv0.y, acc0);
        acc0 = fmaf(xv0.z, wv0.z, acc0);
        acc0 = fmaf(xv0.w, wv0.w, acc0);
        acc1 = fmaf(xv1.x, wv1.x, acc1);
        acc1 = fmaf(xv1.y, wv1.y, acc1);
        acc1 = fmaf(xv1.z, wv1.z, acc1);
        acc1 = fmaf(xv1.w, wv1.w, acc1);
    }
    float acc = acc0 + acc1;

    // wave-64 butterfly reduction
    #pragma unroll
    for (int off = 32; off > 0; off >>= 1) {
        acc += __shfl_xor(acc, off, 64);
    }

    if (lane == 0) {
        float h = tanhf(acc + b[0]);
        out[row] = tanhf(h);
    }
}

extern "C" void kernel_launch(void* const* d_in, const int* in_sizes, int n_in,
                              void* d_out, int out_size, void* d_ws, size_t ws_size,
                              hipStream_t stream) {
    const float* x = (const float*)d_in[0];
    const float* w = (const float*)d_in[1];
    const float* b = (const float*)d_in[2];
    float* out = (float*)d_out;

    // 4 rows per 256-thread block (one wave per row); 16384 rows exactly.
    dim3 grid(BATCH / 4);
    dim3 block(256);
    cartnn_matvec_tanh<<<grid, block, 0, stream>>>(x, w, b, out);
}

// Round 7
// 330.904 us; speedup vs baseline: 1.0600x; 1.0600x over previous
//
#include <hip/hip_runtime.h>
#include <hip/hip_bf16.h>
#include <math.h>

// out[b] = tanh(tanh(dot(x[b,:], w) + b0)), x: [16384, 4096] f32, w: [4096] f32, b: [1] f32
// HBM-bound streamed matvec (AI ~= 0.125 FLOP/B). Roofline: 268 MB / 6.3 TB/s ~= 43 us.
// One 64-lane wave per row, grid-stride over rows (2048 persistent blocks),
// nontemporal float4 loads for x (no reuse), normal loads for w (L1-resident 16 KiB).
//
// NOTE: __builtin_nontemporal_load requires a Clang NATIVE vector type --
// HIP's float4 (HIP_vector_type) is rejected. Use ext_vector_type(4).

#define BATCH    16384
#define IN_SIZE  4096
#define VEC4     (IN_SIZE / 4)   // 1024 float4 per row
#define NBLOCKS  2048            // G11 cap: 256 CU x 8 blocks/CU
#define NWAVES   (NBLOCKS * 4)   // 8192 waves -> 2 rows per wave

typedef float f32x4 __attribute__((ext_vector_type(4)));

__global__ __launch_bounds__(256) void cartnn_matvec_tanh(
    const float* __restrict__ x,
    const float* __restrict__ w,
    const float* __restrict__ b,
    float* __restrict__ out)
{
    const int lane  = threadIdx.x & 63;
    const int gwave = blockIdx.x * 4 + (threadIdx.x >> 6);   // global wave id, 0..8191
    const f32x4* __restrict__ w4 = reinterpret_cast<const f32x4*>(w);
    const float bias = b[0];

    for (int row = gwave; row < BATCH; row += NWAVES) {
        const f32x4* __restrict__ x4 =
            reinterpret_cast<const f32x4*>(x) + (size_t)row * VEC4;

        // 1024 float4 / 64 lanes = 16 iters; 2-deep unroll for ILP.
        float acc0 = 0.0f, acc1 = 0.0f;
        #pragma unroll
        for (int k = lane; k < VEC4; k += 128) {
            f32x4 xv0 = __builtin_nontemporal_load(x4 + k);        // streamed, no reuse
            f32x4 wv0 = w4[k];                                     // L1-resident
            f32x4 xv1 = __builtin_nontemporal_load(x4 + k + 64);
            f32x4 wv1 = w4[k + 64];
            acc0 = fmaf(xv0.x, wv0.x, acc0);
            acc0 = fmaf(xv0.y, wv0.y, acc0);
            acc0 = fmaf(xv0.z, wv0.z, acc0);
            acc0 = fmaf(xv0.w, wv0.w, acc0);
            acc1 = fmaf(xv1.x, wv1.x, acc1);
            acc1 = fmaf(xv1.y, wv1.y, acc1);
            acc1 = fmaf(xv1.z, wv1.z, acc1);
            acc1 = fmaf(xv1.w, wv1.w, acc1);
        }
        float acc = acc0 + acc1;

        // wave-64 butterfly reduction
        #pragma unroll
        for (int off = 32; off > 0; off >>= 1) {
            acc += __shfl_xor(acc, off, 64);
        }

        if (lane == 0) {
            float h = tanhf(acc + bias);
            out[row] = tanhf(h);
        }
    }
}

extern "C" void kernel_launch(void* const* d_in, const int* in_sizes, int n_in,
                              void* d_out, int out_size, void* d_ws, size_t ws_size,
                              hipStream_t stream) {
    const float* x = (const float*)d_in[0];
    const float* w = (const float*)d_in[1];
    const float* b = (const float*)d_in[2];
    float* out = (float*)d_out;

    cartnn_matvec_tanh<<<dim3(NBLOCKS), dim3(256), 0, stream>>>(x, w, b, out);
}